// Round 8
// baseline (230.501 us; speedup 1.0000x reference)
//
#include <hip/hip_runtime.h>
#include <hip/hip_bf16.h>

// Grouped GEMM: out[n,g,k] = sum_d x[n*8+g, d] * W[g, k, d]
// Round 8: BM=128 BN=256 BK=32, 8 waves (2Mx4N, 64x64/wave, acc 4x4 = 64 reg).
//  - A: bf16 in LDS via micro reg-staging (2 f32x4 loads + 1 ds_write_b128
//    per thread per K-tile), 2-K-tile-deep load pipeline (counted vmcnt).
//  - B: bf16 image in d_ws (cvt_w pre-pass), staged with global_load_lds.
//  - 64-B LDS rows, XOR involution chunk ^= (row>>1)&3 -> ALL access
//    patterns bank-conflict-free (fixes R7's 2.5e7 conflicts).
//  - LDS 48 KiB static, regs <=128 -> 2 blocks/CU (4 waves/SIMD).
//  - ONE barrier per K-tile; manual s_waitcnt vmcnt(2) keeps next-next A
//    loads in flight across it (B glds issued first; FENCE-pinned order).

namespace {

constexpr int NG   = 8;
constexpr int DIN  = 1024;
constexpr int DOUT = 1024;
constexpr int BM   = 128;
constexpr int BN   = 256;
constexpr int BK   = 32;
constexpr int NKT  = DIN / BK;            // 32
constexpr int ROWB  = BK * 2;             // 64 B per LDS row (bf16)
constexpr int ATILE = BM * ROWB;          // 8 KiB
constexpr int BTILE = BN * ROWB;          // 16 KiB
constexpr int JTN  = DOUT / BN;           // 4
constexpr size_t WSB_BYTES = (size_t)NG * JTN * NKT * BTILE;  // 16.78 MB

typedef __attribute__((ext_vector_type(8))) short bf16x8;
typedef __attribute__((ext_vector_type(4))) float f32x4;

__device__ __forceinline__ bf16x8 pack_bf16x8v(f32x4 lo, f32x4 hi) {
  union { __hip_bfloat162 h2[4]; bf16x8 v; } p;
  p.h2[0] = __float22bfloat162_rn(make_float2(lo.x, lo.y));
  p.h2[1] = __float22bfloat162_rn(make_float2(lo.z, lo.w));
  p.h2[2] = __float22bfloat162_rn(make_float2(hi.x, hi.y));
  p.h2[3] = __float22bfloat162_rn(make_float2(hi.z, hi.w));
  return p.v;
}

__device__ __forceinline__ void glds16(const void* g, void* l) {
  __builtin_amdgcn_global_load_lds(
      (const __attribute__((address_space(1))) unsigned int*)g,
      (__attribute__((address_space(3))) unsigned int*)l, 16, 0, 0);
}

#define FENCE() asm volatile("" ::: "memory")
#define BAR()   do { FENCE(); __builtin_amdgcn_s_barrier(); FENCE(); } while (0)
#define LGKM0() asm volatile("s_waitcnt lgkmcnt(0)" ::: "memory")
#define VM0()   asm volatile("s_waitcnt vmcnt(0)" ::: "memory")
#define VMC2()  asm volatile("s_waitcnt vmcnt(2)" ::: "memory")
#define MFMA_(a, b, c) __builtin_amdgcn_mfma_f32_16x16x32_bf16((a), (b), (c), 0, 0, 0)

// ---------------- cvt_w: W f32 -> bf16 swizzled B-image --------------------
// one thread per 16-B dest granule. tile = (g*4+jt)*32+kt, 1024 granules/tile.
// granule (r, w) holds source k-chunk (w ^ ((r>>1)&3)).
__global__ __launch_bounds__(256)
void cvt_w_kernel(const float* __restrict__ W, char* __restrict__ wsB) {
  const int q    = (int)blockIdx.x * 256 + (int)threadIdx.x;
  const int tile = q >> 10;
  const int qi   = q & 1023;
  const int r    = qi >> 2;            // B-tile row (out-col within panel)
  const int w    = qi & 3;             // dest granule in row
  const int g    = tile >> 7;
  const int jt   = (tile >> 5) & 3;
  const int kt   = tile & 31;

  const float* src = W + (size_t)(g * DOUT + jt * BN + r) * DIN
                       + kt * BK + ((w ^ ((r >> 1) & 3)) * 8);
  f32x4 lo = *(const f32x4*)(src);
  f32x4 hi = *(const f32x4*)(src + 4);
  *(bf16x8*)(wsB + (size_t)q * 16) = pack_bf16x8v(lo, hi);
}

// ---------------- K-tile body (static buffer index: rule #20) --------------
#define KBODY(T, CUR)                                                          \
  {                                                                            \
    const int t_ = (T);                                                        \
    char* const cA = smA + (CUR) * ATILE;                                      \
    char* const cB = smB + (CUR) * BTILE;                                      \
    char* const nA = smA + (1 - (CUR)) * ATILE;                                \
    char* const nB = smB + (1 - (CUR)) * BTILE;                                \
    const bool st1 = (t_ + 1) < NKT;                                           \
    const bool st2 = (t_ + 2) < NKT;                                           \
    if (WSB) {                                                                 \
      if (st1) {  /* B glds FIRST: must be older than A loads for VMC2 */      \
        const char* Bn = BgT + (size_t)(t_ + 1) * BTILE;                       \
        glds16(Bn + tid * 16, nB + tid * 16);                                  \
        glds16(Bn + 8192 + tid * 16, nB + 8192 + tid * 16);                    \
      }                                                                        \
      FENCE();                                                                 \
    }                                                                          \
    if (st2) {  /* A(t+2) loads: in flight ~2 K-tiles */                       \
      const float* An = aSrc + (size_t)(t_ + 2) * BK;                          \
      aS[CUR][0] = *(const f32x4*)(An);                                        \
      aS[CUR][1] = *(const f32x4*)(An + 4);                                    \
    }                                                                          \
    if (!WSB && st1) {                                                         \
      const float* Bn = bSrc + (size_t)(t_ + 1) * BK;                          \
      bS[0] = *(const f32x4*)(Bn);                                             \
      bS[1] = *(const f32x4*)(Bn + 4);                                         \
      bS[2] = *(const f32x4*)(Bn + (size_t)128 * DIN);                         \
      bS[3] = *(const f32x4*)(Bn + (size_t)128 * DIN + 4);                     \
    }                                                                          \
    FENCE();                                                                   \
    bf16x8 bfr[4];                                                             \
    _Pragma("unroll")                                                          \
    for (int n = 0; n < 4; ++n)                                                \
      bfr[n] = *(const bf16x8*)(cB + boff + n * 1024);                         \
    __builtin_amdgcn_s_setprio(1);                                             \
    _Pragma("unroll")                                                          \
    for (int m = 0; m < 4; ++m) {                                              \
      bf16x8 am = *(const bf16x8*)(cA + aoff + m * 1024);                      \
      _Pragma("unroll")                                                        \
      for (int n = 0; n < 4; ++n)                                              \
        acc[m][n] = MFMA_(am, bfr[n], acc[m][n]);                              \
    }                                                                          \
    __builtin_amdgcn_s_setprio(0);                                             \
    if (st1) {                                                                 \
      /* cvt+write A(t+1): compiler emits COUNTED vmcnt (4 newer in flight) */ \
      *(bf16x8*)(nA + tid * 16) = pack_bf16x8v(aS[1 - (CUR)][0],               \
                                               aS[1 - (CUR)][1]);              \
      if (!WSB) {                                                              \
        *(bf16x8*)(nB + tid * 16)        = pack_bf16x8v(bS[0], bS[1]);         \
        *(bf16x8*)(nB + tid * 16 + 8192) = pack_bf16x8v(bS[2], bS[3]);         \
      }                                                                        \
      LGKM0();                                                                 \
      if (WSB) { if (st2) { VMC2(); } else { VM0(); } }                        \
      BAR();                                                                   \
    }                                                                          \
  }

// ---------------- gemm ------------------------------------------------------
template <bool WSB>
__global__ __launch_bounds__(512, 4)
void gemm_k(const float* __restrict__ X, const float* __restrict__ W,
            const char* __restrict__ wsB, float* __restrict__ O) {
  __shared__ __align__(16) char smA[2 * ATILE];   // 16 KiB bf16, swizzled
  __shared__ __align__(16) char smB[2 * BTILE];   // 32 KiB bf16, swizzled

  // ---- block mapping: group == XCD (2048 blocks, 256/XCD), bijective
  const int bid = (int)blockIdx.x;
  const int swz = (bid & 7) * 256 + (bid >> 3);
  const int jt = swz & 3;                 // col panel [0,4) fastest (A reuse)
  const int it = (swz >> 2) & 63;         // row tile  [0,64)
  const int g  = swz >> 8;                // group     [0,8)  == XCD

  const int n0 = it * BM;
  const int c0 = jt * BN;

  const int tid  = (int)threadIdx.x;
  const int lane = tid & 63;
  const int wid  = tid >> 6;              // 8 waves: 2(M) x 4(N)
  const int wr   = wid >> 2;
  const int wc   = wid & 3;
  const int fr   = lane & 15;
  const int fq   = lane >> 4;

  // ---- A staging: thread -> (row tid>>2, dest granule tid&3), linear dest
  // tid*16; SOURCE chunk = (tid&3) ^ ((row>>1)&3)  [= (tid>>3)&3].
  {
  }
  const int aRow = tid >> 2;
  const int aChk = (tid & 3) ^ ((tid >> 3) & 3);
  const float* aSrc = X + ((size_t)(n0 + aRow) * NG + g) * DIN + aChk * 8;

  // ---- B: image stream (WSB) or raw W reg-staging (fallback)
  const char* BgT = wsB + (size_t)((g * JTN + jt) * NKT) * BTILE;
  const int bRow = tid >> 2;              // fallback rows bRow, bRow+128
  const int bChk = (tid & 3) ^ ((tid >> 3) & 3);
  const float* bSrc = W + (size_t)(g * DOUT + c0 + bRow) * DIN + bChk * 8;

  // ---- fragment LDS addressing: chunk fq lives at phys (fq ^ ((row>>1)&3));
  // row>>1 & 3 == (fr>>1)&3 for all fragment rows (base mult of 16).
  const int psw  = (fq ^ ((fr >> 1) & 3)) << 4;
  const int aoff = (wr * 64 + fr) * ROWB + psw;
  const int boff = (wc * 64 + fr) * ROWB + psw;

  f32x4 aS[2][2];
  f32x4 bS[4];
  f32x4 acc[4][4];
#pragma unroll
  for (int m = 0; m < 4; ++m)
#pragma unroll
    for (int n = 0; n < 4; ++n) acc[m][n] = (f32x4){0.f, 0.f, 0.f, 0.f};

  // ---- prologue: A(0)->aS[0], B(0) glds, A(1)->aS[1]; cvt A(0); publish
  aS[0][0] = *(const f32x4*)(aSrc);
  aS[0][1] = *(const f32x4*)(aSrc + 4);
  if (WSB) {
    glds16(BgT + tid * 16, smB + tid * 16);
    glds16(BgT + 8192 + tid * 16, smB + 8192 + tid * 16);
  } else {
    bS[0] = *(const f32x4*)(bSrc);
    bS[1] = *(const f32x4*)(bSrc + 4);
    bS[2] = *(const f32x4*)(bSrc + (size_t)128 * DIN);
    bS[3] = *(const f32x4*)(bSrc + (size_t)128 * DIN + 4);
  }
  FENCE();
  aS[1][0] = *(const f32x4*)(aSrc + BK);
  aS[1][1] = *(const f32x4*)(aSrc + BK + 4);
  FENCE();
  *(bf16x8*)(smA + tid * 16) = pack_bf16x8v(aS[0][0], aS[0][1]);
  if (!WSB) {
    *(bf16x8*)(smB + tid * 16)        = pack_bf16x8v(bS[0], bS[1]);
    *(bf16x8*)(smB + tid * 16 + 8192) = pack_bf16x8v(bS[2], bS[3]);
  }
  LGKM0();
  if (WSB) { VMC2(); }   // B(0) retired; A(1) pair may stay in flight
  BAR();

  for (int tt = 0; tt < NKT; tt += 2) {
    KBODY(tt, 0);
    KBODY(tt + 1, 1);
  }

  // ---- epilogue: C/D layout col = lane&15, row = (lane>>4)*4 + reg (m89)
#pragma unroll
  for (int m = 0; m < 4; ++m) {
#pragma unroll
    for (int r = 0; r < 4; ++r) {
      const int row = wr * 64 + m * 16 + fq * 4 + r;
      float* orow = O + ((size_t)(n0 + row) * NG + g) * DOUT + c0 + wc * 64;
#pragma unroll
      for (int n = 0; n < 4; ++n) {
        orow[n * 16 + fr] = acc[m][n][r];
      }
    }
  }
}

} // namespace

extern "C" void kernel_launch(void* const* d_in, const int* in_sizes, int n_in,
                              void* d_out, int out_size, void* d_ws, size_t ws_size,
                              hipStream_t stream) {
  (void)n_in; (void)out_size;
  const float* X = (const float*)d_in[0];
  const float* W = (const float*)d_in[1];
  float* O = (float*)d_out;

  const int tokens_total = in_sizes[0] / DIN;            // 65536
  const int ntok_per_g   = tokens_total / NG;            // 8192
  const int grid = NG * (ntok_per_g / BM) * (DOUT / BN); // 2048

  if (ws_size >= WSB_BYTES) {
    const int cvt_grid = (int)(WSB_BYTES / 16 / 256);    // 4096
    cvt_w_kernel<<<dim3(cvt_grid), dim3(256), 0, stream>>>(W, (char*)d_ws);
    gemm_k<true><<<dim3(grid), dim3(512), 0, stream>>>(
        X, W, (const char*)d_ws, O);
  } else {
    gemm_k<false><<<dim3(grid), dim3(512), 0, stream>>>(
        X, W, nullptr, O);
  }
}